// Round 11
// baseline (342.440 us; speedup 1.0000x reference)
//
#include <hip/hip_runtime.h>

// LSTM: HIDDEN=128, SEQ=7, BATCH=65536. fp32 in/out.
// fp16 MFMA GEMM per timestep, c state in registers, h staged via LDS,
// double-buffered, 1 barrier/timestep.
//
// R2-R7: spill fixes, BT=32, dbuf single-barrier, pure-fp16 h, fused-rcp
//        epilogue. Best: 147us @ (256,2).
// R8: persistent-B -> 1 wave/SIMD, 207us: throughput ~ resident waves.
// R9: (256,4) cap 64 < demand -> 1.7GB spills, 463us. cap = 256/N.
// R10: BT=16 @ (256,2): spill-free VGPR 112 but still 2-wave tier; doubled
//      per-wave overhead -> 171us. Achieved waves/SIMD tracks the
//      launch_bounds 2nd arg: 1->11.5%, 2->21%, 4->44.7%.
// R11: BT=16 @ (256,3) (cap ~85): request the 3-wave tier. Shave demand:
//      drop vestigial hn0 hold — with dbuf, s=0's h stages into Ah[nxt]
//      immediately (nxt was last read before the previous barrier).

#define SEQ 7
#define BT 16
#define L2E 1.442695041f  // log2(e)

typedef _Float16 half8 __attribute__((ext_vector_type(8)));
typedef float floatx4 __attribute__((ext_vector_type(4)));

__device__ __forceinline__ floatx4 mfma16(half8 a, half8 b, floatx4 c) {
  return __builtin_amdgcn_mfma_f32_16x16x32_f16(a, b, c, 0, 0, 0);
}

// Pack W_hh [512][128] fp32 into fragment-major fp16, PRE-SCALED by
// log2e (gates i,f,o) or 2*log2e (gate g) so the epilogue uses bare exp2.
// B-operand layout for mfma_f32_16x16x32_f16: lane = kq*16 + col holds
// B[k = kq*8 + jj][n = col] for the 16-col tile.
__global__ void pack_kernel(const float* __restrict__ Whh,
                            _Float16* __restrict__ Bp) {
  int idx = blockIdx.x * 256 + threadIdx.x;   // 0..65535 = j*128 + k
  int j = idx >> 7, k = idx & 127;
  int g = j >> 7;                             // gate group 0..3 (i,f,g,o)
  float sc = (g == 2) ? 2.0f * L2E : L2E;
  _Float16 hi = (_Float16)(Whh[idx] * sc);
  int nt = j >> 4, col = j & 15;              // 16-col N-tile, col within
  int kk = k >> 5, r = k & 31;                // 32-K step, k within
  int kq = r >> 3, jj = r & 7;
  int base = (((nt << 2) + kk) * 64 + (kq << 4) + col) * 8 + jj;
  Bp[base] = hi;
}

__launch_bounds__(256, 3)
__global__ void lstm_kernel(const float* __restrict__ x,
                            const float* __restrict__ x0,
                            const float* __restrict__ Wih,
                            const float* __restrict__ bih,
                            const float* __restrict__ bhh,
                            const float* __restrict__ Wout,
                            const float* __restrict__ boutp,
                            const _Float16* __restrict__ Bp,
                            float* __restrict__ out) {
  // h staged as fp16, double-buffered: [buf][row][k] with +8 pad
  // (272B stride -> conflict-free ds_read_b128 A-fragments, 16B aligned).
  __shared__ _Float16 Ah[2][BT][136];
  __shared__ float xs[2][BT];
  __shared__ float predp[2][4][BT];

  const int tid = threadIdx.x;
  const int w = tid >> 6;          // wave 0..3: owns hc [32w, 32w+32)
  const int lane = tid & 63;
  const int col = lane & 15;
  const int quad = lane >> 4;
  const int rowbase = blockIdx.x * BT;

  // zero h state buf0 (h0 = 0)
  {
    unsigned int* a0 = (unsigned int*)&Ah[0][0][0];
    for (int i = tid; i < BT * 136 / 2; i += 256) a0[i] = 0u;
  }
  if (tid < BT) xs[0][tid] = x0[rowbase + tid];  // input for t=0

  // per-lane constants: gate col j = g*128 + w*32 + s*16 + col,
  // pre-scaled by log2e (2*log2e for gate g) to feed exp2 directly.
  float wih_r[4][2], bias_r[4][2];
#pragma unroll
  for (int g = 0; g < 4; ++g) {
    const float sc = (g == 2) ? 2.0f * L2E : L2E;
#pragma unroll
    for (int s = 0; s < 2; ++s) {
      int j = g * 128 + w * 32 + s * 16 + col;
      wih_r[g][s] = Wih[j] * sc;
      bias_r[g][s] = (bih[j] + bhh[j]) * sc;
    }
  }
  float wout_r[2];
  wout_r[0] = Wout[w * 32 + col];
  wout_r[1] = Wout[w * 32 + 16 + col];
  const float bout = boutp[0];

  float c_r[2][4];  // [s][reg] cell state, fp32, in registers
#pragma unroll
  for (int s = 0; s < 2; ++s)
#pragma unroll
    for (int r = 0; r < 4; ++r) c_r[s][r] = 0.f;

  float pp[4];   // pred partial

  __syncthreads();  // prologue: buf0 + xs[0] ready

#pragma unroll 1
  for (int t = 0; t < SEQ; ++t) {
    const int cur = t & 1, nxt = cur ^ 1;

    // drain pred of t-1 (predp[nxt] complete as of last barrier)
    if (t > 0 && tid < BT) {
      float p = predp[nxt][0][tid] + predp[nxt][1][tid] +
                predp[nxt][2][tid] + predp[nxt][3][tid] + bout;
      out[(size_t)(rowbase + tid) * 7 + (t - 1)] = p;
    }
    // prefetch input for t+1 into the other xs buffer
    if (t + 1 < SEQ && tid < BT) {
      xs[nxt][tid] = x[(size_t)(rowbase + tid) * 7 + t];
    }

#pragma unroll
    for (int s = 0; s < 2; ++s) {
      floatx4 acc[4];  // [g]
#pragma unroll
      for (int g = 0; g < 4; ++g)
        acc[g] = (floatx4){0.f, 0.f, 0.f, 0.f};

#pragma unroll
      for (int kk = 0; kk < 4; ++kk) {
        const int k0 = kk * 32 + quad * 8;
        half8 ah = *(const half8*)&Ah[cur][col][k0];  // A: m = lane&15
#pragma unroll
        for (int g = 0; g < 4; ++g) {
          const int nt = g * 8 + w * 2 + s;
          half8 bhi = *(const half8*)(Bp + ((nt * 4 + kk) * 64 + lane) * 8);
          acc[g] = mfma16(ah, bhi, acc[g]);
        }
      }

#pragma unroll
      for (int r = 0; r < 4; ++r) {
        const int b_loc = quad * 4 + r;  // C row
        const float xv = xs[cur][b_loc];
        // gates pre-scaled: G' = G*log2e (i,f,o) / G*2log2e (g)
        float Gi = acc[0][r] + (xv * wih_r[0][s] + bias_r[0][s]);
        float Gf = acc[1][r] + (xv * wih_r[1][s] + bias_r[1][s]);
        float Gg = acc[2][r] + (xv * wih_r[2][s] + bias_r[2][s]);
        float Go = acc[3][r] + (xv * wih_r[3][s] + bias_r[3][s]);
        // fused-reciprocal cell update (5 exp2 + 2 rcp per element):
        // i*g + f*c = [c(1+A)(1+C) + (1-C)(1+B)] / [(1+A)(1+B)(1+C)]
        float A = exp2f(-Gi);
        float B = exp2f(-Gf);
        float C = exp2f(-Gg);
        float a1 = 1.0f + A, b1 = 1.0f + B, c1 = 1.0f + C;
        float ac = a1 * c1;
        float num = c_r[s][r] * ac + (1.0f - C) * b1;
        float cn = num * __builtin_amdgcn_rcpf(ac * b1);
        c_r[s][r] = cn;
        // h = o * tanh(cn) = (1-E) / [(1+D)(1+E)]
        float D = exp2f(-Go);
        float E = exp2f(cn * (-2.0f * L2E));
        float hn = (1.0f - E) *
                   __builtin_amdgcn_rcpf((1.0f + D) * (1.0f + E));
        // stage h_new (fp16) into the NEXT buffer immediately — safe with
        // dbuf: Ah[nxt] was last read before the previous barrier.
        Ah[nxt][b_loc][w * 32 + s * 16 + col] = (_Float16)hn;
        if (s == 0) {
          pp[r] = hn * wout_r[0];
        } else {
          pp[r] += hn * wout_r[1];
          // reduce pred over the 16 cols this wave holds for this row
          float v = pp[r];
          v += __shfl_xor(v, 1, 64);
          v += __shfl_xor(v, 2, 64);
          v += __shfl_xor(v, 4, 64);
          v += __shfl_xor(v, 8, 64);
          if (col == 0) predp[cur][w][b_loc] = v;
        }
      }
    }
    __syncthreads();  // single barrier: staging, predp, xs prefetch complete
  }

  // drain pred of t=6 (predp[(SEQ-1)&1] = predp[0])
  if (tid < BT) {
    float p = predp[0][0][tid] + predp[0][1][tid] +
              predp[0][2][tid] + predp[0][3][tid] + bout;
    out[(size_t)(rowbase + tid) * 7 + (SEQ - 1)] = p;
  }
}

extern "C" void kernel_launch(void* const* d_in, const int* in_sizes, int n_in,
                              void* d_out, int out_size, void* d_ws, size_t ws_size,
                              hipStream_t stream) {
  const float* x    = (const float*)d_in[0];
  const float* x0   = (const float*)d_in[1];
  const float* Wih  = (const float*)d_in[2];
  const float* Whh  = (const float*)d_in[3];
  const float* bih  = (const float*)d_in[4];
  const float* bhh  = (const float*)d_in[5];
  const float* Wout = (const float*)d_in[6];
  const float* bout = (const float*)d_in[7];
  float* out = (float*)d_out;
  _Float16* Bp = (_Float16*)d_ws;  // 128 KB fragment-major W_hh (fp16)

  pack_kernel<<<256, 256, 0, stream>>>(Whh, Bp);
  lstm_kernel<<<65536 / BT, 256, 0, stream>>>(x, x0, Wih, bih, bhh, Wout, bout,
                                              Bp, out);
}

// Round 12
// 254.290 us; speedup vs baseline: 1.3467x; 1.3467x over previous
//
#include <hip/hip_runtime.h>

// LSTM: HIDDEN=128, SEQ=7, BATCH=65536. fp32 in/out.
// fp16 MFMA GEMM per timestep, c state in registers, h staged via LDS,
// double-buffered, 1 barrier/timestep. BT=32 @ (256,2) — the proven point.
//
// R2-R7: spill fixes, BT=32, dbuf single-barrier, pure-fp16 h, fused-rcp
//        epilogue. Best: 147us @ (256,2), VALU-busy 81us chip-total.
// R8-R11: occupancy ladder mapped: tier N -> VGPR cap 256/N; tier 3+
//        unreachable spill-free; BT=16 carries +40% total VALU. Dead ends.
// R12: cut VALU work at the R7 point: (1) exp2-folded weights (-4 mul/elem),
//      (2) bias + x*W_ih preloaded into MFMA C operand (-4 add/elem, free
//      since acc init writes existed anyway), (3) immediate h staging.

#define SEQ 7
#define BT 32
#define L2E 1.442695041f  // log2(e)

typedef _Float16 half8 __attribute__((ext_vector_type(8)));
typedef float floatx4 __attribute__((ext_vector_type(4)));

__device__ __forceinline__ floatx4 mfma16(half8 a, half8 b, floatx4 c) {
  return __builtin_amdgcn_mfma_f32_16x16x32_f16(a, b, c, 0, 0, 0);
}

// Pack W_hh [512][128] fp32 into fragment-major fp16, PRE-SCALED by
// log2e (gates i,f,o) or 2*log2e (gate g) so the epilogue uses bare exp2.
// B-operand layout for mfma_f32_16x16x32_f16: lane = kq*16 + col holds
// B[k = kq*8 + jj][n = col] for the 16-col tile.
__global__ void pack_kernel(const float* __restrict__ Whh,
                            _Float16* __restrict__ Bp) {
  int idx = blockIdx.x * 256 + threadIdx.x;   // 0..65535 = j*128 + k
  int j = idx >> 7, k = idx & 127;
  int g = j >> 7;                             // gate group 0..3 (i,f,g,o)
  float sc = (g == 2) ? 2.0f * L2E : L2E;
  _Float16 hi = (_Float16)(Whh[idx] * sc);
  int nt = j >> 4, col = j & 15;              // 16-col N-tile, col within
  int kk = k >> 5, r = k & 31;                // 32-K step, k within
  int kq = r >> 3, jj = r & 7;
  int base = (((nt << 2) + kk) * 64 + (kq << 4) + col) * 8 + jj;
  Bp[base] = hi;
}

__launch_bounds__(256, 2)
__global__ void lstm_kernel(const float* __restrict__ x,
                            const float* __restrict__ x0,
                            const float* __restrict__ Wih,
                            const float* __restrict__ bih,
                            const float* __restrict__ bhh,
                            const float* __restrict__ Wout,
                            const float* __restrict__ boutp,
                            const _Float16* __restrict__ Bp,
                            float* __restrict__ out) {
  // h staged as fp16, double-buffered: [buf][row][k] with +8 pad
  // (272B stride -> conflict-free ds_read_b128 A-fragments, 16B aligned).
  __shared__ _Float16 Ah[2][BT][136];
  __shared__ float xs[2][BT];
  __shared__ float predp[2][4][BT];

  const int tid = threadIdx.x;
  const int w = tid >> 6;          // wave 0..3: owns hc [32w, 32w+32)
  const int lane = tid & 63;
  const int col = lane & 15;
  const int quad = lane >> 4;
  const int rowbase = blockIdx.x * BT;

  // zero h state buf0 (h0 = 0)
  {
    unsigned int* a0 = (unsigned int*)&Ah[0][0][0];
    for (int i = tid; i < BT * 136 / 2; i += 256) a0[i] = 0u;
  }
  if (tid < BT) xs[0][tid] = x0[rowbase + tid];  // input for t=0

  // per-lane constants: gate col j = g*128 + w*32 + s*16 + col,
  // pre-scaled by log2e (2*log2e for gate g) to feed exp2 directly.
  float wih_r[4][2], bias_r[4][2];
#pragma unroll
  for (int g = 0; g < 4; ++g) {
    const float sc = (g == 2) ? 2.0f * L2E : L2E;
#pragma unroll
    for (int s = 0; s < 2; ++s) {
      int j = g * 128 + w * 32 + s * 16 + col;
      wih_r[g][s] = Wih[j] * sc;
      bias_r[g][s] = (bih[j] + bhh[j]) * sc;
    }
  }
  float wout_r[2];
  wout_r[0] = Wout[w * 32 + col];
  wout_r[1] = Wout[w * 32 + 16 + col];
  const float bout = boutp[0];

  float c_r[2][2][4];  // [mt][s][reg] cell state, fp32, in registers
#pragma unroll
  for (int mt = 0; mt < 2; ++mt)
#pragma unroll
    for (int s = 0; s < 2; ++s)
#pragma unroll
      for (int r = 0; r < 4; ++r) c_r[mt][s][r] = 0.f;

  float pp[2][4];  // pred partial

  __syncthreads();  // prologue: buf0 + xs[0] ready

#pragma unroll 1
  for (int t = 0; t < SEQ; ++t) {
    const int cur = t & 1, nxt = cur ^ 1;

    // drain pred of t-1 (predp[nxt] complete as of last barrier)
    if (t > 0 && tid < BT) {
      float p = predp[nxt][0][tid] + predp[nxt][1][tid] +
                predp[nxt][2][tid] + predp[nxt][3][tid] + bout;
      out[(size_t)(rowbase + tid) * 7 + (t - 1)] = p;
    }
    // prefetch input for t+1 into the other xs buffer
    if (t + 1 < SEQ && tid < BT) {
      xs[nxt][tid] = x[(size_t)(rowbase + tid) * 7 + t];
    }

    // this lane's 8 batch rows' inputs (LDS broadcast reads)
    float xv_r[2][4];
#pragma unroll
    for (int mt = 0; mt < 2; ++mt)
#pragma unroll
      for (int r = 0; r < 4; ++r)
        xv_r[mt][r] = xs[cur][mt * 16 + quad * 4 + r];

#pragma unroll
    for (int s = 0; s < 2; ++s) {
      // acc pre-initialized with x*W_ih + bias (pre-scaled): the GEMM
      // accumulates on top via the C operand of the first MFMA.
      floatx4 acc[2][4];  // [mt][g]
#pragma unroll
      for (int mt = 0; mt < 2; ++mt)
#pragma unroll
        for (int g = 0; g < 4; ++g)
#pragma unroll
          for (int r = 0; r < 4; ++r)
            acc[mt][g][r] = xv_r[mt][r] * wih_r[g][s] + bias_r[g][s];

#pragma unroll
      for (int kk = 0; kk < 4; ++kk) {
        half8 ah[2];
        const int k0 = kk * 32 + quad * 8;
#pragma unroll
        for (int mt = 0; mt < 2; ++mt) {
          const int row = mt * 16 + col;  // A: m = lane&15 within tile
          ah[mt] = *(const half8*)&Ah[cur][row][k0];
        }
#pragma unroll
        for (int g = 0; g < 4; ++g) {
          const int nt = g * 8 + w * 2 + s;
          half8 bhi = *(const half8*)(Bp + ((nt * 4 + kk) * 64 + lane) * 8);
#pragma unroll
          for (int mt = 0; mt < 2; ++mt)
            acc[mt][g] = mfma16(ah[mt], bhi, acc[mt][g]);
        }
      }

#pragma unroll
      for (int mt = 0; mt < 2; ++mt) {
#pragma unroll
        for (int r = 0; r < 4; ++r) {
          const int b_loc = mt * 16 + quad * 4 + r;  // C row
          // gates already include bias + x-term, pre-scaled for exp2
          float Gi = acc[mt][0][r];
          float Gf = acc[mt][1][r];
          float Gg = acc[mt][2][r];
          float Go = acc[mt][3][r];
          // fused-reciprocal cell update (5 exp2 + 2 rcp per element):
          // i*g + f*c = [c(1+A)(1+C) + (1-C)(1+B)] / [(1+A)(1+B)(1+C)]
          float A = exp2f(-Gi);
          float B = exp2f(-Gf);
          float C = exp2f(-Gg);
          float a1 = 1.0f + A, b1 = 1.0f + B, c1 = 1.0f + C;
          float ac = a1 * c1;
          float num = c_r[mt][s][r] * ac + (1.0f - C) * b1;
          float cn = num * __builtin_amdgcn_rcpf(ac * b1);
          c_r[mt][s][r] = cn;
          // h = o * tanh(cn) = (1-E) / [(1+D)(1+E)]
          float D = exp2f(-Go);
          float E = exp2f(cn * (-2.0f * L2E));
          float hn = (1.0f - E) *
                     __builtin_amdgcn_rcpf((1.0f + D) * (1.0f + E));
          // stage h_new (fp16) into the NEXT buffer immediately — safe
          // with dbuf: Ah[nxt] was last read before the previous barrier.
          Ah[nxt][b_loc][w * 32 + s * 16 + col] = (_Float16)hn;
          if (s == 0) {
            pp[mt][r] = hn * wout_r[0];
          } else {
            pp[mt][r] += hn * wout_r[1];
            // reduce pred over the 16 cols this wave holds for this row
            float v = pp[mt][r];
            v += __shfl_xor(v, 1, 64);
            v += __shfl_xor(v, 2, 64);
            v += __shfl_xor(v, 4, 64);
            v += __shfl_xor(v, 8, 64);
            if (col == 0) predp[cur][w][b_loc] = v;
          }
        }
      }
    }
    __syncthreads();  // single barrier: staging, predp, xs prefetch complete
  }

  // drain pred of t=6 (predp[(SEQ-1)&1] = predp[0])
  if (tid < BT) {
    float p = predp[0][0][tid] + predp[0][1][tid] +
              predp[0][2][tid] + predp[0][3][tid] + bout;
    out[(size_t)(rowbase + tid) * 7 + (SEQ - 1)] = p;
  }
}

extern "C" void kernel_launch(void* const* d_in, const int* in_sizes, int n_in,
                              void* d_out, int out_size, void* d_ws, size_t ws_size,
                              hipStream_t stream) {
  const float* x    = (const float*)d_in[0];
  const float* x0   = (const float*)d_in[1];
  const float* Wih  = (const float*)d_in[2];
  const float* Whh  = (const float*)d_in[3];
  const float* bih  = (const float*)d_in[4];
  const float* bhh  = (const float*)d_in[5];
  const float* Wout = (const float*)d_in[6];
  const float* bout = (const float*)d_in[7];
  float* out = (float*)d_out;
  _Float16* Bp = (_Float16*)d_ws;  // 128 KB fragment-major W_hh (fp16)

  pack_kernel<<<256, 256, 0, stream>>>(Whh, Bp);
  lstm_kernel<<<65536 / BT, 256, 0, stream>>>(x, x0, Wih, bih, bhh, Wout, bout,
                                              Bp, out);
}